// Round 11
// baseline (180.874 us; speedup 1.0000x reference)
//
#include <hip/hip_runtime.h>
#include <hip/hip_fp16.h>
#include <cstdint>

#define IN_F   4096
#define OUT_F  4096
#define BS     64      // sparsity block size
#define NB     64      // blocks per weight dim
#define N_TOK  8192
#define TM     256     // token tile per workgroup (4 waves x 64 rows)
#define NMT    (N_TOK / TM)   // 32 token tiles

typedef __attribute__((ext_vector_type(8))) _Float16       f16x8;
typedef __attribute__((ext_vector_type(8))) unsigned short u16x8;
typedef __attribute__((ext_vector_type(4))) float          f32x4;

// wave-uniform ballot of the block-constant mask row `br`: bit kb set iff
// block (br,kb) is kept. Deterministic.
__device__ __forceinline__ unsigned long long mask_ballot(
        const float* __restrict__ mask, int br, int lane) {
    float mv = mask[(size_t)(br * BS) * IN_F + (size_t)lane * BS];
    return __ballot(mv != 0.0f);
}

// pack 8 fp32 (two f32x4) -> 8 fp16 (RNE), bit pattern in u16x8
__device__ __forceinline__ u16x8 pack8(f32x4 a, f32x4 b) {
    u16x8 o;
#pragma unroll
    for (int j = 0; j < 4; ++j) o[j]     = __half_as_ushort(__float2half_rn(a[j]));
#pragma unroll
    for (int j = 0; j < 4; ++j) o[4 + j] = __half_as_ushort(__float2half_rn(b[j]));
    return o;
}

// ---------------------------------------------------------------------------
// Fully fused block-sparse GEMM: out = x @ (W o mask)^T + bias, fp16 MFMA.
// Single kernel, no workspace.
//   - A (x): direct global->reg->cvt->frag. Wave wv owns rows [wv*64,wv*64+64);
//     each lane loads its 8 MFMA a-frags (2 f32x4 each) straight from x.
//     Per (mr,ks) the wave's 64 lanes cover 16 rows x full 128B lines.
//   - B (W): reg-staged into XOR-swizzled LDS (slot ^= row&7 in 16B units),
//     double-buffered; T14 async-split (issue loads early, commit late).
//   - Phase-per-mt XCD chunk: 64 co-resident WGs (one phase) share ONE mt's
//     4 MB fp32 x-slab = exactly one XCD L2. W loads + out stores are
//     nontemporal so streaming traffic doesn't evict the x-slab.
// ---------------------------------------------------------------------------
__global__ __launch_bounds__(256, 2)
void bsr_fused2_kernel(const float* __restrict__ x,
                       const float* __restrict__ w,
                       const float* __restrict__ bias,
                       const float* __restrict__ mask,
                       float* __restrict__ out) {
    __shared__ unsigned short wsb[2][BS * BS];   // 2 x 8 KB fp16 W block

    const int b     = blockIdx.x;     // 0..2047
    const int xcd   = b & 7;
    const int j     = b >> 3;         // 0..255
    const int phase = j >> 6;         // 0..3
    const int br    = j & 63;
    const int mt    = xcd * 4 + phase;

    const int tid  = threadIdx.x;
    const int lane = tid & 63;
    const int wv   = tid >> 6;        // wave id 0..3 -> rows [wv*64, wv*64+64)
    const int fr   = lane & 15;
    const int kg   = lane >> 4;

    const int mbase = mt * TM;
    const int obase = br * BS;

    unsigned long long ball = mask_ballot(mask, br, lane);
    const int cnt = __popcll(ball);

    f32x4 acc[4][4];
#pragma unroll
    for (int a = 0; a < 4; ++a)
#pragma unroll
        for (int c = 0; c < 4; ++c) acc[a][c] = (f32x4)0.0f;

    // in-flight register staging
    f32x4 ra[8][2];   // A: 8 frags (mr*2+ks) x 2 f32x4
    f32x4 rb[2][2];   // B: 2 groups x 2 f32x4

    // issue B loads for block kb (nontemporal: zero reuse inside WG)
    auto issueB = [&](int kb) {
#pragma unroll
        for (int l = 0; l < 2; ++l) {
            int g = tid + l * 256, row = g >> 3, slot = g & 7;
            const f32x4* src = (const f32x4*)(w + (size_t)(obase + row) * IN_F
                                              + kb * BS + slot * 8);
            rb[l][0] = __builtin_nontemporal_load(src);
            rb[l][1] = __builtin_nontemporal_load(src + 1);
        }
    };
    // issue A loads for block kb (cached: 64 WGs share this x-slab via L2)
    auto issueA = [&](int kb) {
#pragma unroll
        for (int mr = 0; mr < 4; ++mr)
#pragma unroll
            for (int ks = 0; ks < 2; ++ks) {
                int row = wv * 64 + mr * 16 + fr;
                const f32x4* src = (const f32x4*)(x + (size_t)(mbase + row) * IN_F
                                                  + kb * BS + ks * 32 + kg * 8);
                ra[mr * 2 + ks][0] = src[0];
                ra[mr * 2 + ks][1] = src[1];
            }
    };
    // convert staged B regs -> swizzled LDS buffer bb
    auto commitB = [&](int bb) {
#pragma unroll
        for (int l = 0; l < 2; ++l) {
            int g = tid + l * 256, row = g >> 3, slot = g & 7;
            u16x8 p = pack8(rb[l][0], rb[l][1]);
            *(u16x8*)&wsb[bb][row * 64 + ((slot ^ (row & 7)) << 3)] = p;
        }
    };

    unsigned long long rem = ball;
    int cur = 0;
    if (cnt > 0) {
        int kb0 = __ffsll(rem) - 1;
        rem &= rem - 1;
        issueB(kb0);
        issueA(kb0);
        commitB(0);          // waits rb arrival (data dep)
        __syncthreads();
    }

    f16x8 af[8];
    for (int si = 0; si < cnt; ++si) {
        // convert A regs -> frags (frees ra for next prefetch)
#pragma unroll
        for (int i = 0; i < 8; ++i) {
            u16x8 t = pack8(ra[i][0], ra[i][1]);
            af[i] = *(f16x8*)&t;
        }
        const bool more = (si + 1 < cnt);
        if (more) {                       // prefetch next block under compute
            int kbn = __ffsll(rem) - 1;
            rem &= rem - 1;
            issueB(kbn);
            issueA(kbn);
        }
        // compute from wsb[cur] + af
#pragma unroll
        for (int ks = 0; ks < 2; ++ks) {
            f16x8 bf[4];
#pragma unroll
            for (int nr = 0; nr < 4; ++nr) {
                int row = nr * 16 + fr;
                bf[nr] = *(const f16x8*)&wsb[cur][row * 64
                          + (((ks * 4 + kg) ^ (row & 7)) << 3)];
            }
#pragma unroll
            for (int mr = 0; mr < 4; ++mr)
#pragma unroll
                for (int nr = 0; nr < 4; ++nr)
                    acc[mr][nr] = __builtin_amdgcn_mfma_f32_16x16x32_f16(
                        af[mr * 2 + ks], bf[nr], acc[mr][nr], 0, 0, 0);
        }
        if (more) commitB(cur ^ 1);       // waits rb; writes other buffer
        __syncthreads();                  // wsb[cur^1] ready; all reads of cur done
        cur ^= 1;
    }

    // ---- epilogue: bias + nontemporal fp32 stores.
    // C/D layout: col = lane&15 (fr), row = kg*4 + r.
#pragma unroll
    for (int nr = 0; nr < 4; ++nr) {
        float bv = bias[obase + nr * 16 + fr];
#pragma unroll
        for (int mr = 0; mr < 4; ++mr) {
#pragma unroll
            for (int r = 0; r < 4; ++r) {
                int m = mbase + wv * 64 + mr * 16 + kg * 4 + r;
                __builtin_nontemporal_store(acc[mr][nr][r] + bv,
                    &out[(size_t)m * OUT_F + obase + nr * 16 + fr]);
            }
        }
    }
}

extern "C" void kernel_launch(void* const* d_in, const int* in_sizes, int n_in,
                              void* d_out, int out_size, void* d_ws, size_t ws_size,
                              hipStream_t stream) {
    const float* x    = (const float*)d_in[0];
    const float* w    = (const float*)d_in[1];
    const float* bias = (const float*)d_in[2];
    const float* mask = (const float*)d_in[3];
    float* out = (float*)d_out;

    bsr_fused2_kernel<<<NMT * NB, 256, 0, stream>>>(x, w, bias, mask, out);
}

// Round 12
// 175.256 us; speedup vs baseline: 1.0321x; 1.0321x over previous
//
#include <hip/hip_runtime.h>
#include <hip/hip_fp16.h>
#include <cstdint>

#define IN_F   4096
#define OUT_F  4096
#define BS     64      // sparsity block size
#define NB     64      // blocks per weight dim
#define N_TOK  8192
#define TM     256     // token tile per workgroup (8 waves x 32 rows)
#define NMT    (N_TOK / TM)   // 32 token tiles

typedef __attribute__((ext_vector_type(8))) _Float16       f16x8;
typedef __attribute__((ext_vector_type(8))) unsigned short u16x8;
typedef __attribute__((ext_vector_type(4))) float          f32x4;

// ---------------- workspace layout ----------------
// wt: 4096 slots (br,si) x 8 KB (u16[64][64], pre-swizzled fp16)
#define WS_WT_BYTES    (4096ull * 8192ull)             // 32 MiB
#define WS_NEEDED      WS_WT_BYTES

// wave-uniform ballot of the block-constant mask row `br`: bit kb set iff
// block (br,kb) is kept. Deterministic; all consumers derive the same
// ascending-kb slot order from it.
__device__ __forceinline__ unsigned long long mask_ballot(
        const float* __restrict__ mask, int br, int lane) {
    float mv = mask[(size_t)(br * BS) * IN_F + (size_t)lane * BS];
    return __ballot(mv != 0.0f);
}

// pack 8 fp32 (two f32x4) -> 8 fp16 (RNE) bit patterns
__device__ __forceinline__ u16x8 pack8(f32x4 a, f32x4 b) {
    u16x8 o;
#pragma unroll
    for (int j = 0; j < 4; ++j) o[j]     = __half_as_ushort(__float2half_rn(a[j]));
#pragma unroll
    for (int j = 0; j < 4; ++j) o[4 + j] = __half_as_ushort(__float2half_rn(b[j]));
    return o;
}

// ---------------------------------------------------------------------------
// Kernel 1: kept W blocks -> packed [br][si] pre-swizzled fp16 tiles
// (u16[64][64], 16B slot' = slot ^ (row&7)). ~410 of 4096 WGs do work; ~3 us.
// wt total = 3.3 MB -> L2/L3-resident for the GEMM.
// ---------------------------------------------------------------------------
__global__ __launch_bounds__(256)
void convert_w_kernel(const float* __restrict__ w,
                      const float* __restrict__ mask,
                      unsigned short* __restrict__ wt) {
    const int br   = blockIdx.y, si = blockIdx.x;
    const int lane = threadIdx.x & 63;
    unsigned long long ball = mask_ballot(mask, br, lane);
    if (si >= __popcll(ball)) return;
    // kb = si-th set bit of ball (prefix-popcount match, wave-uniform result)
    bool fl = ((ball >> lane) & 1ull) &&
              (__popcll(ball & ((1ull << lane) - 1ull)) == si);
    unsigned long long m2 = __ballot(fl);
    const int kb = __ffsll(m2) - 1;
    unsigned short* tile = wt + (size_t)(br * NB + si) * 4096;

    float4 va[2], vb[2];
#pragma unroll
    for (int l = 0; l < 2; ++l) {
        int g   = threadIdx.x + l * 256;             // 0..511
        int row = g >> 3, slot = g & 7;
        const float* src = w + (size_t)(br * BS + row) * IN_F + kb * BS + slot * 8;
        va[l] = *(const float4*)src;
        vb[l] = *(const float4*)(src + 4);
    }
#pragma unroll
    for (int l = 0; l < 2; ++l) {
        int g   = threadIdx.x + l * 256;
        int row = g >> 3, slot = g & 7;
        u16x8 p = pack8(*(f32x4*)&va[l], *(f32x4*)&vb[l]);
        *(u16x8*)&tile[row * 64 + ((slot ^ (row & 7)) << 3)] = p;
    }
}

// ---------------------------------------------------------------------------
// Kernel 2: fused block-sparse GEMM, BARRIER-FREE.
//   out = x @ (W o mask)^T + bias,  fp16 MFMA, fp32 accumulate.
// 8 waves x (32 rows x 64 cols) per WG; per wave-iter:
//   A: 8x f32x4 direct from x (global->reg->cvt) — identical element order
//      to the r4-r10 LDS path; B: 8x f16x8 direct from pre-swizzled wt.
//   16 MFMA. No LDS, no __syncthreads -> no vmcnt(0) drain; TLP hides latency.
// Phase-chunked XCD map: 64 co-resident WGs share one mt's 4 MB x-slab (L2)
// and the whole 3.3 MB wt.
// ---------------------------------------------------------------------------
__global__ __launch_bounds__(512, 4)
void bsr_fused3_kernel(const float* __restrict__ x,
                       const unsigned short* __restrict__ wt,
                       const float* __restrict__ bias,
                       const float* __restrict__ mask,
                       float* __restrict__ out) {
    const int b     = blockIdx.x;     // 0..2047
    const int xcd   = b & 7;
    const int j     = b >> 3;         // 0..255
    const int phase = j >> 6;         // 0..3
    const int br    = j & 63;
    const int mt    = xcd * 4 + phase;

    const int tid  = threadIdx.x;
    const int lane = tid & 63;
    const int wv   = tid >> 6;        // 0..7 -> rows [wv*32, wv*32+32)
    const int fr   = lane & 15;
    const int kg   = lane >> 4;

    const int mbase = mt * TM;
    const int obase = br * BS;

    unsigned long long ball = mask_ballot(mask, br, lane);
    const int cnt = __popcll(ball);

    f32x4 acc[2][4];
#pragma unroll
    for (int a = 0; a < 2; ++a)
#pragma unroll
        for (int c = 0; c < 4; ++c) acc[a][c] = (f32x4)0.0f;

    const unsigned short* wbr = wt + (size_t)br * NB * 4096;
    const float* xw = x + (size_t)mbase * IN_F;

    unsigned long long rem = ball;
    for (int si = 0; si < cnt; ++si) {
        const int kb = __ffsll(rem) - 1;
        rem &= rem - 1;

        // ---- issue all A loads (8 x f32x4) ----
        f32x4 ra[4][2];
#pragma unroll
        for (int mr = 0; mr < 2; ++mr)
#pragma unroll
            for (int ks = 0; ks < 2; ++ks) {
                const f32x4* src = (const f32x4*)(xw
                    + (size_t)(wv * 32 + mr * 16 + fr) * IN_F
                    + kb * BS + ks * 32 + kg * 8);
                ra[mr * 2 + ks][0] = src[0];
                ra[mr * 2 + ks][1] = src[1];
            }
        // ---- issue all B loads (8 x f16x8, pre-swizzled wt) ----
        f16x8 bq[2][4];
#pragma unroll
        for (int ks = 0; ks < 2; ++ks)
#pragma unroll
            for (int nr = 0; nr < 4; ++nr) {
                int row = nr * 16 + fr;
                bq[ks][nr] = *(const f16x8*)&wbr[(size_t)si * 4096
                    + row * 64 + (((ks * 4 + kg) ^ (row & 7)) << 3)];
            }
        // ---- convert + MFMA ----
#pragma unroll
        for (int ks = 0; ks < 2; ++ks)
#pragma unroll
            for (int mr = 0; mr < 2; ++mr) {
                u16x8 t = pack8(ra[mr * 2 + ks][0], ra[mr * 2 + ks][1]);
                f16x8 af = *(f16x8*)&t;
#pragma unroll
                for (int nr = 0; nr < 4; ++nr)
                    acc[mr][nr] = __builtin_amdgcn_mfma_f32_16x16x32_f16(
                        af, bq[ks][nr], acc[mr][nr], 0, 0, 0);
            }
    }

    // ---- epilogue: bias + fp32 stores. C/D: col=lane&15, row=kg*4+r ----
#pragma unroll
    for (int nr = 0; nr < 4; ++nr) {
        float bv = bias[obase + nr * 16 + fr];
#pragma unroll
        for (int mr = 0; mr < 2; ++mr) {
#pragma unroll
            for (int r = 0; r < 4; ++r) {
                int m = mbase + wv * 32 + mr * 16 + kg * 4 + r;
                out[(size_t)m * OUT_F + obase + nr * 16 + fr] = acc[mr][nr][r] + bv;
            }
        }
    }
}

// ---------------------------------------------------------------------------
// Fallback (ws too small): r10's fused in-loop conversion kernel.
// ---------------------------------------------------------------------------
__global__ __launch_bounds__(256, 3)
void bsr_fused_kernel(const float* __restrict__ x,
                      const float* __restrict__ w,
                      const float* __restrict__ bias,
                      const float* __restrict__ mask,
                      float* __restrict__ out) {
    __shared__ unsigned short xs[128 * BS];
    __shared__ unsigned short wsb[BS * BS];

    const int mt   = blockIdx.x;
    const int br   = blockIdx.y;
    const int tid  = threadIdx.x;
    const int lane = tid & 63;
    const int wv   = tid >> 6;
    const int fr   = lane & 15;
    const int kg   = lane >> 4;

    const int mbase = mt * 128;
    const int obase = br * BS;

    unsigned long long ball = mask_ballot(mask, br, lane);
    const int cnt = __popcll(ball);
    unsigned long long rem = ball;

    f32x4 acc[2][4];
#pragma unroll
    for (int a = 0; a < 2; ++a)
#pragma unroll
        for (int c = 0; c < 4; ++c) acc[a][c] = (f32x4)0.0f;

    for (int si = 0; si < cnt; ++si) {
        const int kb = __ffsll(rem) - 1;
        rem &= rem - 1;
        const int kbase = kb * BS;
#pragma unroll
        for (int l = 0; l < 4; ++l) {
            int g = tid + l * 256;
            int row = g >> 3, slot = g & 7;
            const float* src = x + (size_t)(mbase + row) * IN_F + kbase + slot * 8;
            f32x4 v0 = *(const f32x4*)src;
            f32x4 v1 = *(const f32x4*)(src + 4);
            *(u16x8*)&xs[row * BS + ((slot ^ (row & 7)) << 3)] = pack8(v0, v1);
        }
#pragma unroll
        for (int l = 0; l < 2; ++l) {
            int g = tid + l * 256;
            int row = g >> 3, slot = g & 7;
            const float* src = w + (size_t)(obase + row) * IN_F + kbase + slot * 8;
            f32x4 v0 = *(const f32x4*)src;
            f32x4 v1 = *(const f32x4*)(src + 4);
            *(u16x8*)&wsb[row * BS + ((slot ^ (row & 7)) << 3)] = pack8(v0, v1);
        }
        __syncthreads();
#pragma unroll
        for (int ks = 0; ks < 2; ++ks) {
            f16x8 a[2], bfr[4];
#pragma unroll
            for (int mr = 0; mr < 2; ++mr) {
                int row = wv * 32 + mr * 16 + fr;
                a[mr] = *(const f16x8*)&xs[row * BS + (((ks * 4 + kg) ^ (row & 7)) << 3)];
            }
#pragma unroll
            for (int nr = 0; nr < 4; ++nr) {
                int row = nr * 16 + fr;
                bfr[nr] = *(const f16x8*)&wsb[row * BS + (((ks * 4 + kg) ^ (row & 7)) << 3)];
            }
#pragma unroll
            for (int mr = 0; mr < 2; ++mr)
#pragma unroll
                for (int nr = 0; nr < 4; ++nr)
                    acc[mr][nr] = __builtin_amdgcn_mfma_f32_16x16x32_f16(
                        a[mr], bfr[nr], acc[mr][nr], 0, 0, 0);
        }
        __syncthreads();
    }

#pragma unroll
    for (int nr = 0; nr < 4; ++nr) {
        float bv = bias[obase + nr * 16 + fr];
#pragma unroll
        for (int mr = 0; mr < 2; ++mr) {
#pragma unroll
            for (int r = 0; r < 4; ++r) {
                int m = mbase + wv * 32 + mr * 16 + kg * 4 + r;
                out[(size_t)m * OUT_F + obase + nr * 16 + fr] = acc[mr][nr][r] + bv;
            }
        }
    }
}

extern "C" void kernel_launch(void* const* d_in, const int* in_sizes, int n_in,
                              void* d_out, int out_size, void* d_ws, size_t ws_size,
                              hipStream_t stream) {
    const float* x    = (const float*)d_in[0];
    const float* w    = (const float*)d_in[1];
    const float* bias = (const float*)d_in[2];
    const float* mask = (const float*)d_in[3];
    float* out = (float*)d_out;

    if (ws_size >= WS_NEEDED) {
        unsigned short* wt = (unsigned short*)d_ws;
        convert_w_kernel<<<dim3(NB, NB), 256, 0, stream>>>(w, mask, wt);
        bsr_fused3_kernel<<<NMT * NB, 512, 0, stream>>>(x, wt, bias, mask, out);
    } else {
        dim3 grid(N_TOK / 128, NB);
        bsr_fused_kernel<<<grid, 256, 0, stream>>>(x, w, bias, mask, out);
    }
}

// Round 13
// 110.376 us; speedup vs baseline: 1.6387x; 1.5878x over previous
//
#include <hip/hip_runtime.h>
#include <hip/hip_fp16.h>
#include <cstdint>

#define IN_F   4096
#define OUT_F  4096
#define BS     64      // sparsity block size
#define NB     64      // blocks per weight dim
#define N_TOK  8192
#define TM     256     // token tile per workgroup (4 waves x 64 rows)
#define NMT    (N_TOK / TM)   // 32 token tiles

typedef __attribute__((ext_vector_type(8))) _Float16       f16x8;
typedef __attribute__((ext_vector_type(8))) unsigned short u16x8;
typedef __attribute__((ext_vector_type(4))) unsigned short u16x4;
typedef __attribute__((ext_vector_type(4))) float          f32x4;

// ---------------- workspace layout (bytes) ----------------
// x16: row-major fp16 copy of x  [8192][4096]        (67.1 MB)
// wt : 4096 slots (br,si) x 8 KB (u16[64][64], pre-swizzled fp16)
#define WS_X16_OFF     0ull
#define WS_X16_BYTES   ((size_t)N_TOK * IN_F * 2ull)      // 67,108,864
#define WS_WT_OFF      (WS_X16_OFF + WS_X16_BYTES)
#define WS_WT_BYTES    (4096ull * 8192ull)                // 32 MiB
#define WS_NEEDED      (WS_WT_OFF + WS_WT_BYTES)          // ~99 MiB

// wave-uniform ballot of the block-constant mask row `br`
__device__ __forceinline__ unsigned long long mask_ballot(
        const float* __restrict__ mask, int br, int lane) {
    float mv = mask[(size_t)(br * BS) * IN_F + (size_t)lane * BS];
    return __ballot(mv != 0.0f);
}

// pack 8 fp32 -> 8 fp16 (RNE) bit patterns
__device__ __forceinline__ u16x8 pack8(f32x4 a, f32x4 b) {
    u16x8 o;
#pragma unroll
    for (int j = 0; j < 4; ++j) o[j]     = __half_as_ushort(__float2half_rn(a[j]));
#pragma unroll
    for (int j = 0; j < 4; ++j) o[4 + j] = __half_as_ushort(__float2half_rn(b[j]));
    return o;
}

// ---------------------------------------------------------------------------
// Kernel 1 (merged convert):
//  blocks [0,4096):   x -> x16, PURE LINEAR STREAM (no transpose, no swizzle:
//                     the GEMM applies the swizzle via per-lane gll sources).
//                     WG b owns 2048 consecutive f32x4; 8 coalesced iters.
//  blocks [4096,8192): kept W blocks -> packed [br][si] pre-swizzled fp16
//                     tiles (~410 active WGs, ~7 MB total).
// ---------------------------------------------------------------------------
__global__ __launch_bounds__(256)
void convert_all_kernel(const float* __restrict__ x,
                        const float* __restrict__ w,
                        const float* __restrict__ mask,
                        unsigned short* __restrict__ x16,
                        unsigned short* __restrict__ wt) {
    const int b = blockIdx.x;
    if (b < 4096) {
        const f32x4* xin = (const f32x4*)x;
        u16x4* xo = (u16x4*)x16;
        const size_t base = (size_t)b * 2048 + threadIdx.x;
#pragma unroll
        for (int it = 0; it < 8; ++it) {
            f32x4 v = xin[base + it * 256];      // 1KB/wave, coalesced
            u16x4 o;
#pragma unroll
            for (int j = 0; j < 4; ++j) o[j] = __half_as_ushort(__float2half_rn(v[j]));
            xo[base + it * 256] = o;             // 512B/wave, coalesced
        }
    } else {
        const int wb   = b - 4096;               // 0..4095
        const int br   = wb >> 6, si = wb & 63;
        const int lane = threadIdx.x & 63;
        unsigned long long ball = mask_ballot(mask, br, lane);
        if (si >= __popcll(ball)) return;
        bool fl = ((ball >> lane) & 1ull) &&
                  (__popcll(ball & ((1ull << lane) - 1ull)) == si);
        unsigned long long m2 = __ballot(fl);
        const int kb = __ffsll(m2) - 1;
        unsigned short* tile = wt + (size_t)(br * NB + si) * 4096;

        f32x4 va[2], vb[2];
#pragma unroll
        for (int l = 0; l < 2; ++l) {
            int g   = threadIdx.x + l * 256;     // 0..511
            int row = g >> 3, slot = g & 7;
            const f32x4* src = (const f32x4*)(w + (size_t)(br * BS + row) * IN_F
                                              + kb * BS + slot * 8);
            va[l] = src[0];
            vb[l] = src[1];
        }
#pragma unroll
        for (int l = 0; l < 2; ++l) {
            int g   = threadIdx.x + l * 256;
            int row = g >> 3, slot = g & 7;
            *(u16x8*)&tile[row * 64 + ((slot ^ (row & 7)) << 3)] = pack8(va[l], vb[l]);
        }
    }
}

// async global->LDS, 16B per lane. LDS dest = uniform base + lane*16;
// global source is PER-LANE (m173: pre-swizzled-source pattern).
__device__ __forceinline__ void gll16(const void* g, void* l) {
    __builtin_amdgcn_global_load_lds(
        (const __attribute__((address_space(1))) unsigned int*)g,
        (__attribute__((address_space(3))) unsigned int*)l, 16, 0, 0);
}

// ---------------------------------------------------------------------------
// Kernel 2: block-sparse GEMM (r8 structure, proven ~35 us).
// A staged from ROW-MAJOR x16 with per-lane swizzled global sources ->
// LDS image identical to r8's packed-tile version. B from packed wt.
// fp16 MFMA, TM=256, wave tile 64x64 (4x4 rep), 2-phase LDS dbuf,
// inline ballot-meta, phase-chunked XCD swizzle.
// ---------------------------------------------------------------------------
__global__ __launch_bounds__(256, 2)
void bsr_mfma6_kernel(const unsigned short* __restrict__ x16,
                      const unsigned short* __restrict__ wt,
                      const float* __restrict__ bias,
                      const float* __restrict__ mask,
                      float* __restrict__ out) {
    __shared__ unsigned short xs[2][TM * BS];   // 2 x 32 KB
    __shared__ unsigned short wsb[2][BS * BS];  // 2 x  8 KB

    const int b     = blockIdx.x;
    const int xcd   = b & 7;
    const int j     = b >> 3;           // 0..255
    const int phase = j >> 7;           // 0..1
    const int idx   = j & 127;          // br-fast within phase
    const int br    = idx >> 1;
    const int mt    = xcd * 4 + phase * 2 + (idx & 1);

    const int tid  = threadIdx.x;
    const int lane = tid & 63;
    const int wv   = tid >> 6;          // wave 0..3 -> A rows [wv*64, wv*64+64)
    const int fr   = lane & 15;
    const int kg   = lane >> 4;

    unsigned long long ball = mask_ballot(mask, br, lane);
    const int cnt = __popcll(ball);

    f32x4 acc[4][4];
#pragma unroll
    for (int a = 0; a < 4; ++a)
#pragma unroll
        for (int c = 0; c < 4; ++c) acc[a][c] = (f32x4)0.0f;

    // per-lane loop-invariant A-source offsets (bytes within the mt slab):
    // gll call q stages rows [wv*64+q*8, +8); lane -> row_local, slotpos.
    // source column block = slotpos ^ (row&7)  => LDS holds swizzled image.
    int preA[8];
#pragma unroll
    for (int q = 0; q < 8; ++q) {
        int rl = wv * 64 + q * 8 + (lane >> 3);
        int s  = (lane & 7) ^ (rl & 7);
        preA[q] = rl * (IN_F * 2) + s * 16;
    }

    const char* xslab = (const char*)x16 + (size_t)(mt * TM) * (IN_F * 2);
    const char* wbase = (const char*)wt;

    // stage K-block kb (slot si) into buffer bb
    auto stage = [&](int kb, int si, int bb) {
        const char* xg = xslab + (size_t)kb * 128;                 // +row-local
        const char* wg = wbase + ((size_t)(br * 64 + si) << 13);   // 8 KB tiles
        char* ldsA = (char*)xs[bb] + wv * 8192;
#pragma unroll
        for (int q = 0; q < 8; ++q)
            gll16(xg + preA[q], ldsA + q * 1024);
        const int bw = wv * 2048;
#pragma unroll
        for (int q = 0; q < 2; ++q)
            gll16(wg + bw + q * 1024 + lane * 16, (char*)wsb[bb] + bw + q * 1024);
    };

    unsigned long long rem = ball;
    int cur = 0;
    if (cnt > 0) {
        int kb0 = __ffsll(rem) - 1;
        rem &= rem - 1;
        stage(kb0, 0, 0);
    }
    __syncthreads();

    for (int si = 0; si < cnt; ++si) {
        if (si + 1 < cnt) {                 // overlap next stage with compute
            int kbn = __ffsll(rem) - 1;
            rem &= rem - 1;
            stage(kbn, si + 1, cur ^ 1);
        }

#pragma unroll
        for (int ks = 0; ks < 2; ++ks) {
            f16x8 a[4], bfr[4];
#pragma unroll
            for (int mr = 0; mr < 4; ++mr) {
                int row = wv * 64 + mr * 16 + fr;
                a[mr] = *(const f16x8*)&xs[cur][row * 64 + (((ks * 4 + kg) ^ (row & 7)) << 3)];
            }
#pragma unroll
            for (int nr = 0; nr < 4; ++nr) {
                int row = nr * 16 + fr;
                bfr[nr] = *(const f16x8*)&wsb[cur][row * 64 + (((ks * 4 + kg) ^ (row & 7)) << 3)];
            }
#pragma unroll
            for (int mr = 0; mr < 4; ++mr)
#pragma unroll
                for (int nr = 0; nr < 4; ++nr)
                    acc[mr][nr] = __builtin_amdgcn_mfma_f32_16x16x32_f16(
                        a[mr], bfr[nr], acc[mr][nr], 0, 0, 0);
        }
        __syncthreads();   // all waves done reading cur; next stage drained
        cur ^= 1;
    }

    // ---- epilogue: bias + fp32 stores. C/D: col=lane&15, row=(lane>>4)*4+r ----
    const int mbase = mt * TM;
    const int obase = br * BS;
#pragma unroll
    for (int nr = 0; nr < 4; ++nr) {
        float bv = bias[obase + nr * 16 + fr];
#pragma unroll
        for (int mr = 0; mr < 4; ++mr) {
#pragma unroll
            for (int r = 0; r < 4; ++r) {
                int m = mbase + wv * 64 + mr * 16 + kg * 4 + r;
                out[(size_t)m * OUT_F + obase + nr * 16 + fr] = acc[mr][nr][r] + bv;
            }
        }
    }
}

// ---------------------------------------------------------------------------
// Fallback (ws too small): fused in-loop conversion, single buffer.
// ---------------------------------------------------------------------------
__global__ __launch_bounds__(256, 3)
void bsr_fused_kernel(const float* __restrict__ x,
                      const float* __restrict__ w,
                      const float* __restrict__ bias,
                      const float* __restrict__ mask,
                      float* __restrict__ out) {
    __shared__ unsigned short xs[128 * BS];
    __shared__ unsigned short wsb[BS * BS];

    const int mt   = blockIdx.x;
    const int br   = blockIdx.y;
    const int tid  = threadIdx.x;
    const int lane = tid & 63;
    const int wv   = tid >> 6;
    const int fr   = lane & 15;
    const int kg   = lane >> 4;

    const int mbase = mt * 128;
    const int obase = br * BS;

    unsigned long long ball = mask_ballot(mask, br, lane);
    const int cnt = __popcll(ball);
    unsigned long long rem = ball;

    f32x4 acc[2][4];
#pragma unroll
    for (int a = 0; a < 2; ++a)
#pragma unroll
        for (int c = 0; c < 4; ++c) acc[a][c] = (f32x4)0.0f;

    for (int si = 0; si < cnt; ++si) {
        const int kb = __ffsll(rem) - 1;
        rem &= rem - 1;
        const int kbase = kb * BS;
#pragma unroll
        for (int l = 0; l < 4; ++l) {
            int g = tid + l * 256;
            int row = g >> 3, slot = g & 7;
            const f32x4* src = (const f32x4*)(x + (size_t)(mbase + row) * IN_F + kbase + slot * 8);
            *(u16x8*)&xs[row * BS + ((slot ^ (row & 7)) << 3)] = pack8(src[0], src[1]);
        }
#pragma unroll
        for (int l = 0; l < 2; ++l) {
            int g = tid + l * 256;
            int row = g >> 3, slot = g & 7;
            const f32x4* src = (const f32x4*)(w + (size_t)(obase + row) * IN_F + kbase + slot * 8);
            *(u16x8*)&wsb[row * BS + ((slot ^ (row & 7)) << 3)] = pack8(src[0], src[1]);
        }
        __syncthreads();
#pragma unroll
        for (int ks = 0; ks < 2; ++ks) {
            f16x8 a[2], bfr[4];
#pragma unroll
            for (int mr = 0; mr < 2; ++mr) {
                int row = wv * 32 + mr * 16 + fr;
                a[mr] = *(const f16x8*)&xs[row * BS + (((ks * 4 + kg) ^ (row & 7)) << 3)];
            }
#pragma unroll
            for (int nr = 0; nr < 4; ++nr) {
                int row = nr * 16 + fr;
                bfr[nr] = *(const f16x8*)&wsb[row * BS + (((ks * 4 + kg) ^ (row & 7)) << 3)];
            }
#pragma unroll
            for (int mr = 0; mr < 2; ++mr)
#pragma unroll
                for (int nr = 0; nr < 4; ++nr)
                    acc[mr][nr] = __builtin_amdgcn_mfma_f32_16x16x32_f16(
                        a[mr], bfr[nr], acc[mr][nr], 0, 0, 0);
        }
        __syncthreads();
    }

#pragma unroll
    for (int nr = 0; nr < 4; ++nr) {
        float bv = bias[obase + nr * 16 + fr];
#pragma unroll
        for (int mr = 0; mr < 2; ++mr) {
#pragma unroll
            for (int r = 0; r < 4; ++r) {
                int m = mbase + wv * 32 + mr * 16 + kg * 4 + r;
                out[(size_t)m * OUT_F + obase + nr * 16 + fr] = acc[mr][nr][r] + bv;
            }
        }
    }
}

extern "C" void kernel_launch(void* const* d_in, const int* in_sizes, int n_in,
                              void* d_out, int out_size, void* d_ws, size_t ws_size,
                              hipStream_t stream) {
    const float* x    = (const float*)d_in[0];
    const float* w    = (const float*)d_in[1];
    const float* bias = (const float*)d_in[2];
    const float* mask = (const float*)d_in[3];
    float* out = (float*)d_out;

    if (ws_size >= WS_NEEDED) {
        unsigned short* x16 = (unsigned short*)((char*)d_ws + WS_X16_OFF);
        unsigned short* wt  = (unsigned short*)((char*)d_ws + WS_WT_OFF);
        convert_all_kernel<<<8192, 256, 0, stream>>>(x, w, mask, x16, wt);
        bsr_mfma6_kernel<<<NMT * NB, 256, 0, stream>>>(x16, wt, bias, mask, out);
    } else {
        dim3 grid(N_TOK / 128, NB);
        bsr_fused_kernel<<<grid, 256, 0, stream>>>(x, w, bias, mask, out);
    }
}